// Round 18
// baseline (704.802 us; speedup 1.0000x reference)
//
#include <hip/hip_runtime.h>

// Problem constants
#define B_  4096
#define T_  64
#define D_  256
#define E_  128
#define H_  256

typedef __attribute__((ext_vector_type(8))) short short8;
typedef __attribute__((ext_vector_type(4))) float f32x4;
typedef __attribute__((ext_vector_type(16))) float f32x16;
typedef __attribute__((ext_vector_type(2))) unsigned int u32x2;

__device__ inline unsigned short f2bf(float f){
  unsigned u = __float_as_uint(f);
  u += 0x7FFFu + ((u >> 16) & 1u);   // RNE
  return (unsigned short)(u >> 16);
}
__device__ inline float bf2f(unsigned short v){
  return __uint_as_float(((unsigned)v) << 16);
}
__device__ inline float sigm_(float x){ return __fdividef(1.f, 1.f + __expf(-x)); }
__device__ inline float tanh_(float x){
  float e = __expf(2.f * fminf(fmaxf(x, -15.f), 15.f));
  return __fdividef(e - 1.f, e + 1.f);
}
__device__ inline short8 ntload8(const unsigned short* p){
  return __builtin_nontemporal_load((const short8*)p);
}
__device__ inline f32x4 ntload4f(const float* p){
  return __builtin_nontemporal_load((const f32x4*)p);
}

// ---------------------------------------------------------------------------
// init: pack weights as 32x32x16 MFMA A-fragments per slice (R12/R13 layout).
// biasc[h*4+q]; zero hgF buf0 (2 MB); zero cnt (256 x 128B lines).
// ---------------------------------------------------------------------------
__global__ __launch_bounds__(256) void init_kernel(
    const float* __restrict__ W_ih, const float* __restrict__ b_ih,
    const float* __restrict__ W_hh, const float* __restrict__ b_hh,
    unsigned short* __restrict__ Wf, float* __restrict__ biasc,
    unsigned short* __restrict__ hgF, int* __restrict__ cnt){
  const int idx  = blockIdx.x*256 + threadIdx.x;
  const int e    = idx & 7;
  const int l    = (idx >> 3) & 63;
  const int fk   = idx >> 9;          // (s*4+nf)*24 + ks
  const int ks   = fk % 24;
  const int nfs  = fk / 24;
  const int nf   = nfs & 3;
  const int s    = nfs >> 2;
  const int r    = l & 31;
  const int q    = r & 3;
  const int hl   = r >> 2;
  const int h    = s*32 + nf*8 + hl;
  const int k    = ks*16 + (l >> 5)*8 + e;
  const int g    = q*H_ + h;
  float v = (k < E_) ? W_ih[g*E_ + k] : W_hh[g*H_ + (k - E_)];
  Wf[idx] = f2bf(v);
  if (idx < 4*H_){
    int hh = idx >> 2, qq = idx & 3, gg = qq*H_ + hh;
    biasc[idx] = b_ih[gg] + b_hh[gg];
  }
  if (idx < 262144) ((unsigned long long*)hgF)[idx] = 0ull;   // buf0 = 2 MB zeros
  if (idx < 8192) cnt[idx] = 0;
}

// ---------------------------------------------------------------------------
// enc: encF = bf16(tanh(x @ W_enc^T + b_enc)) in B-fragment order (R12).
// ---------------------------------------------------------------------------
__global__ __launch_bounds__(256) void enc_kernel(
    const float* __restrict__ x, const float* __restrict__ W_enc,
    const float* __restrict__ b_enc, unsigned short* __restrict__ encF){
  __shared__ unsigned short As[128*64];
  __shared__ unsigned short Bs[128*64];
  __shared__ float bes[128];
  const int tid = threadIdx.x;
  const int lane = tid & 63, w = tid >> 6;
  const int l15 = lane & 15, lq = lane >> 4;
  const int m0 = blockIdx.x * 128;
  if (tid < 128) bes[tid] = b_enc[tid];

  f32x4 acc[16];
  #pragma unroll
  for (int i=0;i<16;i++) acc[i] = (f32x4)0.f;

  for (int kc = 0; kc < 4; ++kc){
    const int kb = kc*64;
    __syncthreads();
    #pragma unroll
    for (int i=0;i<4;i++){
      int u = i*256 + tid; int r = u>>3, sx = u&7;
      const float* sp = x + (size_t)(m0+r)*D_ + kb + sx*8;
      f32x4 v0 = ntload4f(sp);
      f32x4 v1 = ntload4f(sp+4);
      short8 pk;
      pk[0]=(short)f2bf(v0[0]); pk[1]=(short)f2bf(v0[1]); pk[2]=(short)f2bf(v0[2]); pk[3]=(short)f2bf(v0[3]);
      pk[4]=(short)f2bf(v1[0]); pk[5]=(short)f2bf(v1[1]); pk[6]=(short)f2bf(v1[2]); pk[7]=(short)f2bf(v1[3]);
      int off = (r*128 + sx*16) ^ ((r&7)<<4);
      *(short8*)((char*)As + off) = pk;
    }
    #pragma unroll
    for (int i=0;i<4;i++){
      int u = i*256 + tid; int r = u>>3, sx = u&7;
      const float* sp = W_enc + (size_t)r*D_ + kb + sx*8;
      f32x4 v0 = *(const f32x4*)sp;
      f32x4 v1 = *(const f32x4*)(sp+4);
      short8 pk;
      pk[0]=(short)f2bf(v0[0]); pk[1]=(short)f2bf(v0[1]); pk[2]=(short)f2bf(v0[2]); pk[3]=(short)f2bf(v0[3]);
      pk[4]=(short)f2bf(v1[0]); pk[5]=(short)f2bf(v1[1]); pk[6]=(short)f2bf(v1[2]); pk[7]=(short)f2bf(v1[3]);
      int off = (r*128 + sx*16) ^ ((r&7)<<4);
      *(short8*)((char*)Bs + off) = pk;
    }
    __syncthreads();
    #pragma unroll
    for (int kk=0;kk<2;kk++){
      short8 af[2];
      #pragma unroll
      for (int mi=0;mi<2;mi++){
        int r = 32*w + mi*16 + l15;
        int off = (r*128 + kk*64 + lq*16) ^ ((r&7)<<4);
        af[mi] = *(const short8*)((const char*)As + off);
      }
      #pragma unroll
      for (int nf=0;nf<8;nf++){
        int r = nf*16 + l15;
        int off = (r*128 + kk*64 + lq*16) ^ ((r&7)<<4);
        short8 bfr = *(const short8*)((const char*)Bs + off);
        #pragma unroll
        for (int mi=0;mi<2;mi++)
          acc[mi*8+nf] = __builtin_amdgcn_mfma_f32_16x16x32_bf16(af[mi], bfr, acc[mi*8+nf], 0,0,0);
      }
    }
  }
  #pragma unroll
  for (int mi=0;mi<2;mi++){
    #pragma unroll
    for (int nf=0;nf<8;nf++){
      int col = nf*16 + l15;
      float be = bes[col];
      #pragma unroll
      for (int j=0;j<4;j++){
        int bt = m0 + 32*w + mi*16 + lq*4 + j;
        int b = bt >> 6, tt = bt & 63;
        int gg = b >> 7, rg = (b >> 5) & 3, l31b = b & 31;
        int kw = col >> 4, l5b = (col >> 3) & 1, ee = col & 7;
        size_t byteoff = ((((size_t)tt*32 + gg)*32 + rg*8 + kw) << 10)
                       + (l31b + 32*l5b)*16 + ee*2;
        *(unsigned short*)((char*)encF + byteoff) = f2bf(tanh_(acc[mi*8+nf][j] + be));
      }
    }
  }
}

// ---------------------------------------------------------------------------
// Gate-split LSTM recurrence (R17 + post-early / bar4 removed):
// - after bar3, repack waves (w<8) store their frags, drain OWN vmcnt, and
//   SELF-POST the slice flag (8 posts/step; consumers wait flag >= 8t).
//   bar4 deleted -> 3 barriers/step; consumer detect+load RTT overlaps our
//   write-pass H instead of following it.
// - race audit: past bar3, G/H touch own-slice frags only; a racing wave's
//   D(t+1) writes non-own frags only (disjoint); E(t) reads done at bar2.
// ---------------------------------------------------------------------------
__global__ __launch_bounds__(1024) void rec_kernel(
    const unsigned short* __restrict__ encF,
    const unsigned short* __restrict__ Wf,
    const float* __restrict__ biasc,
    const float* __restrict__ x,
    unsigned short* __restrict__ hgF,     // 2 bufs x [32 g][64 frag][1 KB]
    int* __restrict__ cnt,                // 256 x (128B line): [g][s]
    unsigned short* __restrict__ psq,     // [63][8][4096] bf16
    float* __restrict__ out_hn,
    float* __restrict__ out_ldim,
    float* __restrict__ out_ldt){
  extern __shared__ char smem[];
  char* wlds = smem;                      // 96 KB weight A-frags
  char* hbuf = smem + 98304;              // 64 KB frag-order [bg*16+ks][1KB]
  const int tid = threadIdx.x, lane = tid & 63, w = tid >> 6;
  const int l31 = lane & 31, l5 = lane >> 5;
  const int s  = blockIdx.x >> 5;
  const int g  = blockIdx.x & 31;
  const int b0 = g * 128;
  const int nf = w & 3, bg = w >> 2;

  // weights -> LDS (coalesced, once); zero hbuf (step-0 h = 0)
  {
    const short8* src = (const short8*)(Wf + (size_t)s*49152);
    short8* dst = (short8*)wlds;
    for (int i = tid; i < 6144; i += 1024) dst[i] = src[i];
    short8* hz = (short8*)hbuf;
    for (int i = tid; i < 4096; i += 1024) hz[i] = (short8)(short)0;
  }

  float biasr[16];
  #pragma unroll
  for (int reg=0; reg<16; ++reg){
    int q = reg & 3, hl = nf*8 + 2*(reg>>2) + l5;
    biasr[reg] = biasc[(s*32 + hl)*4 + q];
  }

  const char* abase = wlds + ((nf*24) << 10) + lane*16;                  // + ks<<10
  const char* ebase = (const char*)encF + (((size_t)(g*32 + bg*8)) << 10) + lane*16;
  const char* hfb   = hbuf + ((bg*16) << 10) + lane*16;                  // + ks<<10

  // write-pass mapping: wave w -> rows w*8..w*8+8, lane&7 -> 4-col chunk
  const int row2 = w*8 + (lane >> 3);
  const int bg2  = row2 >> 5;
  const int cloc = (lane & 7)*4;          // col within slice [0,32)
  const int hfo  = ((bg2*16 + s*2 + (cloc>>4)) << 10)
                 + ((row2 & 31) + ((cloc & 15) >> 3)*32)*16 + (cloc & 7)*2;
  const float* xr = x + (size_t)(b0+row2)*T_*D_ + s*32 + cloc;
  float* ltr = out_ldt + (size_t)(b0+row2)*T_*H_ + s*32 + cloc;

  // spin sources for this wave: slices {2*(w&3), 2*(w&3)+1} minus own
  const int sA = 2*(w&3), sB = sA + 1;

  float c[4] = {0.f,0.f,0.f,0.f};
  f32x4 ldim = (f32x4)0.f;

  __syncthreads();   // wlds + hbuf ready

  for (int t=0; t<T_; ++t){
    // A. prefetch enc frags + x stripe (flag-independent)
    short8 ef[8];
    #pragma unroll
    for (int kw=0;kw<8;kw++)
      ef[kw] = ntload8((const unsigned short*)(ebase + ((size_t)t<<20) + (kw<<10)));
    f32x4 xv = (f32x4)0.f;
    if (t < T_-1) xv = ntload4f(xr + (size_t)(t+1)*D_);

    // B. enc-part MFMA (cover while flags settle)
    f32x16 a = (f32x16)0.f;
    #pragma unroll
    for (int ks=0; ks<8; ++ks){
      short8 A = *(const short8*)(abase + (ks<<10));
      a = __builtin_amdgcn_mfma_f32_32x32x16_bf16(A, ef[ks], a, 0,0,0);
    }

    // C. per-wave spin on this wave's 2 source slices (lane0 polls).
    // flag counts 8 posts per producer step -> target 8*t.
    if (t > 0 && lane == 0){
      if (sA != s){
        int guard = 0;
        while (__hip_atomic_load(cnt + (g*8+sA)*32, __ATOMIC_RELAXED,
                                 __HIP_MEMORY_SCOPE_AGENT) < 8*t){
          if (++guard > (1<<20)) break;   // bail -> wrong result, not a hang
          __builtin_amdgcn_s_sleep(1);
        }
      }
      if (sB != s){
        int guard = 0;
        while (__hip_atomic_load(cnt + (g*8+sB)*32, __ATOMIC_RELAXED,
                                 __HIP_MEMORY_SCOPE_AGENT) < 8*t){
          if (++guard > (1<<20)) break;
          __builtin_amdgcn_s_sleep(1);
        }
      }
    }

    // D. stage this wave's frags (skip own slice). 16B coherent loads.
    const size_t cbuf = ((size_t)(t&1)) << 21;
    short8 dv0, dv1, dv2, dv3;
    {
      const char* pb = (const char*)hgF + cbuf + (((size_t)(g*64 + w*4)) << 10) + lane*16;
      if (((w*4+0) & 15) >> 1 != s)
        asm volatile("global_load_dwordx4 %0, %1, off sc0 sc1" : "=&v"(dv0) : "v"(pb)        : "memory");
      if (((w*4+1) & 15) >> 1 != s)
        asm volatile("global_load_dwordx4 %0, %1, off sc0 sc1" : "=&v"(dv1) : "v"(pb+1024)   : "memory");
      if (((w*4+2) & 15) >> 1 != s)
        asm volatile("global_load_dwordx4 %0, %1, off sc0 sc1" : "=&v"(dv2) : "v"(pb+2048)   : "memory");
      if (((w*4+3) & 15) >> 1 != s)
        asm volatile("global_load_dwordx4 %0, %1, off sc0 sc1" : "=&v"(dv3) : "v"(pb+3072)   : "memory");
    }
    asm volatile("s_waitcnt vmcnt(0)" ::: "memory");
    __builtin_amdgcn_sched_barrier(0);
    {
      char* db = hbuf + ((w*4) << 10) + lane*16;
      if (((w*4+0) & 15) >> 1 != s) *(short8*)(db)        = dv0;
      if (((w*4+1) & 15) >> 1 != s) *(short8*)(db + 1024) = dv1;
      if (((w*4+2) & 15) >> 1 != s) *(short8*)(db + 2048) = dv2;
      if (((w*4+3) & 15) >> 1 != s) *(short8*)(db + 3072) = dv3;
    }
    __syncthreads();   // bar1: hbuf fully staged

    // E. h-part MFMA (B-frags contiguous from LDS, conflict-free)
    #pragma unroll
    for (int ks=0; ks<16; ++ks){
      short8 A  = *(const short8*)(abase + ((8+ks)<<10));
      short8 Bv = *(const short8*)(hfb + (ks<<10));
      a = __builtin_amdgcn_mfma_f32_32x32x16_bf16(A, Bv, a, 0,0,0);
    }
    __syncthreads();   // bar2: all hbuf reads done

    // F. pointwise -> h(t+1) overlay into own-slice frags
    #pragma unroll
    for (int r2=0; r2<4; ++r2){
      float gi = sigm_(a[r2*4+0] + biasr[r2*4+0]);
      float gf = sigm_(a[r2*4+1] + biasr[r2*4+1]);
      float gg = tanh_(a[r2*4+2] + biasr[r2*4+2]);
      float go = sigm_(a[r2*4+3] + biasr[r2*4+3]);
      float cn = gf*c[r2] + gi*gg;
      c[r2] = cn;
      float hn = go * tanh_(cn);
      int hl = nf*8 + 2*r2 + l5;          // col within slice [0,32)
      int fr = bg*16 + s*2 + (hl>>4);
      int cl = hl & 15;
      *(unsigned short*)(hbuf + (fr<<10) + (l31 + ((cl>>3)<<5))*16 + (cl&7)*2) = f2bf(hn);
    }
    __syncthreads();   // bar3: overlay complete (LAST barrier of the step)

    // G. repack own-slice frags -> hgF[(t+1)&1]; per-wave drain + SELF-POST
    if (t < T_-1 && w < 8){
      int bgr = w >> 1, kwl = w & 1;
      int fr = bgr*16 + s*2 + kwl;
      short8 hv8 = *(const short8*)(hbuf + (fr<<10) + lane*16);
      union { short8 sv; unsigned long long u[2]; } cv; cv.sv = hv8;
      unsigned long long* dstp = (unsigned long long*)((char*)hgF
          + (((size_t)((t+1)&1))<<21)
          + (((size_t)(g*64 + fr)) << 10) + lane*16);
      __hip_atomic_store(dstp,   cv.u[0], __ATOMIC_RELAXED, __HIP_MEMORY_SCOPE_AGENT);
      __hip_atomic_store(dstp+1, cv.u[1], __ATOMIC_RELAXED, __HIP_MEMORY_SCOPE_AGENT);
      asm volatile("s_waitcnt vmcnt(0)" ::: "memory");
      __builtin_amdgcn_sched_barrier(0);
      if (lane == 0)
        __hip_atomic_fetch_add(cnt + (g*8+s)*32, 1, __ATOMIC_RELAXED,
                               __HIP_MEMORY_SCOPE_AGENT);
    }

    // H. write-pass (after post: consumer RTT overlaps these stores)
    u32x2 hb = *(const u32x2*)(hbuf + hfo);
    f32x4 hf;
    hf[0] = bf2f((unsigned short)(hb[0] & 0xFFFFu));
    hf[1] = bf2f((unsigned short)(hb[0] >> 16));
    hf[2] = bf2f((unsigned short)(hb[1] & 0xFFFFu));
    hf[3] = bf2f((unsigned short)(hb[1] >> 16));
    float* ltp = ltr + (size_t)t*H_;
    if (t < T_-1){
      f32x4 d;
      d[0] = fabsf(hf[0] - xv[0]);
      d[1] = fabsf(hf[1] - xv[1]);
      d[2] = fabsf(hf[2] - xv[2]);
      d[3] = fabsf(hf[3] - xv[3]);
      __builtin_nontemporal_store(d, (f32x4*)ltp);
      ldim += d;
      float ss = d[0]*d[0] + d[1]*d[1] + d[2]*d[2] + d[3]*d[3];
      ss += __shfl_xor(ss, 1);
      ss += __shfl_xor(ss, 2);
      ss += __shfl_xor(ss, 4);
      if ((lane & 7) == 0)
        psq[((size_t)t*8 + s)*4096 + b0 + row2] = f2bf(ss);
    } else {
      __builtin_nontemporal_store((f32x4)0.f, (f32x4*)ltp);
      __builtin_nontemporal_store(hf,
          (f32x4*)(out_hn + (size_t)(b0+row2)*H_ + s*32 + cloc));
    }
  }

  // epilogue: loss_dim
  *(f32x4*)(out_ldim + (size_t)(b0+row2)*H_ + s*32 + cloc) = ldim * (1.f/63.f);
}

// ---------------------------------------------------------------------------
// final: loss[b] = (1/63) sum_t sqrt(sum_s psq[t][s][b]).
// grid 64 x 256: 4 waves split t-range, LDS combine.
// ---------------------------------------------------------------------------
__global__ __launch_bounds__(256) void final_kernel(
    const unsigned short* __restrict__ psq, float* __restrict__ out_loss){
  __shared__ float part[4][64];
  const int w = threadIdx.x >> 6, lane = threadIdx.x & 63;
  const int b = blockIdx.x*64 + lane;
  const int t0 = w*16;
  const int nt = (w==3) ? 15 : 16;
  float lacc = 0.f;
  for (int ti=0; ti<nt; ++ti){
    int t = t0 + ti;
    float sum = 0.f;
    #pragma unroll
    for (int s=0;s<8;s++) sum += bf2f(psq[((size_t)t*8 + s)*4096 + b]);
    lacc += sqrtf(sum);
  }
  part[w][lane] = lacc;
  __syncthreads();
  if (w == 0)
    out_loss[b] = (part[0][lane]+part[1][lane]+part[2][lane]+part[3][lane])
                  * (1.f/63.f);
}

// ---------------------------------------------------------------------------
extern "C" void kernel_launch(void* const* d_in, const int* in_sizes, int n_in,
                              void* d_out, int out_size, void* d_ws, size_t ws_size,
                              hipStream_t stream){
  const float* x     = (const float*)d_in[0];
  const float* W_enc = (const float*)d_in[1];
  const float* b_enc = (const float*)d_in[2];
  const float* W_ih  = (const float*)d_in[3];
  const float* b_ih  = (const float*)d_in[4];
  const float* W_hh  = (const float*)d_in[5];
  const float* b_hh  = (const float*)d_in[6];

  // ws: encF 64MB | Wf 768KB | biasc 4KB | hgF 4MB | cnt 32KB | psq 4MB
  char* ws = (char*)d_ws;
  unsigned short* encF  = (unsigned short*)(ws);                 // 67,108,864
  unsigned short* Wf    = (unsigned short*)(ws + 67108864);      //    786,432
  float*          biasc = (float*)         (ws + 67895296);      //      4,096
  unsigned short* hgF   = (unsigned short*)(ws + 67899392);      //  4,194,304
  int*            cnt   = (int*)           (ws + 72093696);      //     32,768
  unsigned short* psq   = (unsigned short*)(ws + 72126464);      //  4,128,768

  float* out_hn   = (float*)d_out;
  float* out_loss = out_hn  + (size_t)B_*H_;
  float* out_ldim = out_loss + B_;
  float* out_ldt  = out_ldim + (size_t)B_*H_;

  (void)hipFuncSetAttribute((const void*)rec_kernel,
      hipFuncAttributeMaxDynamicSharedMemorySize, 163840);

  init_kernel<<<1536, 256, 0, stream>>>(W_ih, b_ih, W_hh, b_hh, Wf, biasc, hgF, cnt);
  enc_kernel<<<2048, 256, 0, stream>>>(x, W_enc, b_enc, encF);
  rec_kernel<<<256, 1024, 163840, stream>>>(encF, Wf, biasc, x, hgF, cnt, psq,
                                            out_hn, out_ldim, out_ldt);
  final_kernel<<<64, 256, 0, stream>>>(psq, out_loss);
}

// Round 19
// 684.874 us; speedup vs baseline: 1.0291x; 1.0291x over previous
//
#include <hip/hip_runtime.h>

// Problem constants
#define B_  4096
#define T_  64
#define D_  256
#define E_  128
#define H_  256

typedef __attribute__((ext_vector_type(8))) short short8;
typedef __attribute__((ext_vector_type(4))) float f32x4;
typedef __attribute__((ext_vector_type(16))) float f32x16;
typedef __attribute__((ext_vector_type(2))) unsigned int u32x2;

__device__ inline unsigned short f2bf(float f){
  unsigned u = __float_as_uint(f);
  u += 0x7FFFu + ((u >> 16) & 1u);   // RNE
  return (unsigned short)(u >> 16);
}
__device__ inline float bf2f(unsigned short v){
  return __uint_as_float(((unsigned)v) << 16);
}
__device__ inline float sigm_(float x){ return __fdividef(1.f, 1.f + __expf(-x)); }
__device__ inline float tanh_(float x){
  float e = __expf(2.f * fminf(fmaxf(x, -15.f), 15.f));
  return __fdividef(e - 1.f, e + 1.f);
}
__device__ inline short8 ntload8(const unsigned short* p){
  return __builtin_nontemporal_load((const short8*)p);
}
__device__ inline f32x4 ntload4f(const float* p){
  return __builtin_nontemporal_load((const f32x4*)p);
}

// ---------------------------------------------------------------------------
// init: pack weights as 32x32x16 MFMA A-fragments per slice (R12/R13 layout).
// biasc[h*4+q]; zero hgF buf0 (2 MB); zero cnt (256 x 128B lines).
// ---------------------------------------------------------------------------
__global__ __launch_bounds__(256) void init_kernel(
    const float* __restrict__ W_ih, const float* __restrict__ b_ih,
    const float* __restrict__ W_hh, const float* __restrict__ b_hh,
    unsigned short* __restrict__ Wf, float* __restrict__ biasc,
    unsigned short* __restrict__ hgF, int* __restrict__ cnt){
  const int idx  = blockIdx.x*256 + threadIdx.x;
  const int e    = idx & 7;
  const int l    = (idx >> 3) & 63;
  const int fk   = idx >> 9;          // (s*4+nf)*24 + ks
  const int ks   = fk % 24;
  const int nfs  = fk / 24;
  const int nf   = nfs & 3;
  const int s    = nfs >> 2;
  const int r    = l & 31;
  const int q    = r & 3;
  const int hl   = r >> 2;
  const int h    = s*32 + nf*8 + hl;
  const int k    = ks*16 + (l >> 5)*8 + e;
  const int g    = q*H_ + h;
  float v = (k < E_) ? W_ih[g*E_ + k] : W_hh[g*H_ + (k - E_)];
  Wf[idx] = f2bf(v);
  if (idx < 4*H_){
    int hh = idx >> 2, qq = idx & 3, gg = qq*H_ + hh;
    biasc[idx] = b_ih[gg] + b_hh[gg];
  }
  if (idx < 262144) ((unsigned long long*)hgF)[idx] = 0ull;   // buf0 = 2 MB zeros
  if (idx < 8192) cnt[idx] = 0;
}

// ---------------------------------------------------------------------------
// enc: encF = bf16(tanh(x @ W_enc^T + b_enc)) in B-fragment order (R12).
// ---------------------------------------------------------------------------
__global__ __launch_bounds__(256) void enc_kernel(
    const float* __restrict__ x, const float* __restrict__ W_enc,
    const float* __restrict__ b_enc, unsigned short* __restrict__ encF){
  __shared__ unsigned short As[128*64];
  __shared__ unsigned short Bs[128*64];
  __shared__ float bes[128];
  const int tid = threadIdx.x;
  const int lane = tid & 63, w = tid >> 6;
  const int l15 = lane & 15, lq = lane >> 4;
  const int m0 = blockIdx.x * 128;
  if (tid < 128) bes[tid] = b_enc[tid];

  f32x4 acc[16];
  #pragma unroll
  for (int i=0;i<16;i++) acc[i] = (f32x4)0.f;

  for (int kc = 0; kc < 4; ++kc){
    const int kb = kc*64;
    __syncthreads();
    #pragma unroll
    for (int i=0;i<4;i++){
      int u = i*256 + tid; int r = u>>3, sx = u&7;
      const float* sp = x + (size_t)(m0+r)*D_ + kb + sx*8;
      f32x4 v0 = ntload4f(sp);
      f32x4 v1 = ntload4f(sp+4);
      short8 pk;
      pk[0]=(short)f2bf(v0[0]); pk[1]=(short)f2bf(v0[1]); pk[2]=(short)f2bf(v0[2]); pk[3]=(short)f2bf(v0[3]);
      pk[4]=(short)f2bf(v1[0]); pk[5]=(short)f2bf(v1[1]); pk[6]=(short)f2bf(v1[2]); pk[7]=(short)f2bf(v1[3]);
      int off = (r*128 + sx*16) ^ ((r&7)<<4);
      *(short8*)((char*)As + off) = pk;
    }
    #pragma unroll
    for (int i=0;i<4;i++){
      int u = i*256 + tid; int r = u>>3, sx = u&7;
      const float* sp = W_enc + (size_t)r*D_ + kb + sx*8;
      f32x4 v0 = *(const f32x4*)sp;
      f32x4 v1 = *(const f32x4*)(sp+4);
      short8 pk;
      pk[0]=(short)f2bf(v0[0]); pk[1]=(short)f2bf(v0[1]); pk[2]=(short)f2bf(v0[2]); pk[3]=(short)f2bf(v0[3]);
      pk[4]=(short)f2bf(v1[0]); pk[5]=(short)f2bf(v1[1]); pk[6]=(short)f2bf(v1[2]); pk[7]=(short)f2bf(v1[3]);
      int off = (r*128 + sx*16) ^ ((r&7)<<4);
      *(short8*)((char*)Bs + off) = pk;
    }
    __syncthreads();
    #pragma unroll
    for (int kk=0;kk<2;kk++){
      short8 af[2];
      #pragma unroll
      for (int mi=0;mi<2;mi++){
        int r = 32*w + mi*16 + l15;
        int off = (r*128 + kk*64 + lq*16) ^ ((r&7)<<4);
        af[mi] = *(const short8*)((const char*)As + off);
      }
      #pragma unroll
      for (int nf=0;nf<8;nf++){
        int r = nf*16 + l15;
        int off = (r*128 + kk*64 + lq*16) ^ ((r&7)<<4);
        short8 bfr = *(const short8*)((const char*)Bs + off);
        #pragma unroll
        for (int mi=0;mi<2;mi++)
          acc[mi*8+nf] = __builtin_amdgcn_mfma_f32_16x16x32_bf16(af[mi], bfr, acc[mi*8+nf], 0,0,0);
      }
    }
  }
  #pragma unroll
  for (int mi=0;mi<2;mi++){
    #pragma unroll
    for (int nf=0;nf<8;nf++){
      int col = nf*16 + l15;
      float be = bes[col];
      #pragma unroll
      for (int j=0;j<4;j++){
        int bt = m0 + 32*w + mi*16 + lq*4 + j;
        int b = bt >> 6, tt = bt & 63;
        int gg = b >> 7, rg = (b >> 5) & 3, l31b = b & 31;
        int kw = col >> 4, l5b = (col >> 3) & 1, ee = col & 7;
        size_t byteoff = ((((size_t)tt*32 + gg)*32 + rg*8 + kw) << 10)
                       + (l31b + 32*l5b)*16 + ee*2;
        *(unsigned short*)((char*)encF + byteoff) = f2bf(tanh_(acc[mi*8+nf][j] + be));
      }
    }
  }
}

// ---------------------------------------------------------------------------
// Gate-split LSTM recurrence (R17 structure, dual-flag single poll loop):
// - hbuf FRAGMENT-ordered [4 bg][16 ks] x 1KB: conflict-free D/E/G.
// - D loads: global_load_dwordx4 sc0 sc1 coherent 16B messages.
// - own-slice frags never staged; H reads own-slice only.
// - G: stores + bar4 (block drain) + single tid0 post (target t) — R17 form.
// 4 barriers/step. 256 blocks x 1024 threads.
// ---------------------------------------------------------------------------
__global__ __launch_bounds__(1024) void rec_kernel(
    const unsigned short* __restrict__ encF,
    const unsigned short* __restrict__ Wf,
    const float* __restrict__ biasc,
    const float* __restrict__ x,
    unsigned short* __restrict__ hgF,     // 2 bufs x [32 g][64 frag][1 KB]
    int* __restrict__ cnt,                // 256 x (128B line): [g][s]
    unsigned short* __restrict__ psq,     // [63][8][4096] bf16
    float* __restrict__ out_hn,
    float* __restrict__ out_ldim,
    float* __restrict__ out_ldt){
  extern __shared__ char smem[];
  char* wlds = smem;                      // 96 KB weight A-frags
  char* hbuf = smem + 98304;              // 64 KB frag-order [bg*16+ks][1KB]
  const int tid = threadIdx.x, lane = tid & 63, w = tid >> 6;
  const int l31 = lane & 31, l5 = lane >> 5;
  const int s  = blockIdx.x >> 5;
  const int g  = blockIdx.x & 31;
  const int b0 = g * 128;
  const int nf = w & 3, bg = w >> 2;

  // weights -> LDS (coalesced, once); zero hbuf (step-0 h = 0)
  {
    const short8* src = (const short8*)(Wf + (size_t)s*49152);
    short8* dst = (short8*)wlds;
    for (int i = tid; i < 6144; i += 1024) dst[i] = src[i];
    short8* hz = (short8*)hbuf;
    for (int i = tid; i < 4096; i += 1024) hz[i] = (short8)(short)0;
  }

  float biasr[16];
  #pragma unroll
  for (int reg=0; reg<16; ++reg){
    int q = reg & 3, hl = nf*8 + 2*(reg>>2) + l5;
    biasr[reg] = biasc[(s*32 + hl)*4 + q];
  }

  const char* abase = wlds + ((nf*24) << 10) + lane*16;                  // + ks<<10
  const char* ebase = (const char*)encF + (((size_t)(g*32 + bg*8)) << 10) + lane*16;
  const char* hfb   = hbuf + ((bg*16) << 10) + lane*16;                  // + ks<<10

  // write-pass mapping: wave w -> rows w*8..w*8+8, lane&7 -> 4-col chunk
  const int row2 = w*8 + (lane >> 3);
  const int bg2  = row2 >> 5;
  const int cloc = (lane & 7)*4;          // col within slice [0,32)
  const int hfo  = ((bg2*16 + s*2 + (cloc>>4)) << 10)
                 + ((row2 & 31) + ((cloc & 15) >> 3)*32)*16 + (cloc & 7)*2;
  const float* xr = x + (size_t)(b0+row2)*T_*D_ + s*32 + cloc;
  float* ltr = out_ldt + (size_t)(b0+row2)*T_*H_ + s*32 + cloc;

  // spin sources for this wave: slices {2*(w&3), 2*(w&3)+1} minus own
  const int sA = 2*(w&3), sB = sA + 1;

  float c[4] = {0.f,0.f,0.f,0.f};
  f32x4 ldim = (f32x4)0.f;

  __syncthreads();   // wlds + hbuf ready

  for (int t=0; t<T_; ++t){
    // A. prefetch enc frags + x stripe (flag-independent)
    short8 ef[8];
    #pragma unroll
    for (int kw=0;kw<8;kw++)
      ef[kw] = ntload8((const unsigned short*)(ebase + ((size_t)t<<20) + (kw<<10)));
    f32x4 xv = (f32x4)0.f;
    if (t < T_-1) xv = ntload4f(xr + (size_t)(t+1)*D_);

    // B. enc-part MFMA (cover while flags settle)
    f32x16 a = (f32x16)0.f;
    #pragma unroll
    for (int ks=0; ks<8; ++ks){
      short8 A = *(const short8*)(abase + (ks<<10));
      a = __builtin_amdgcn_mfma_f32_32x32x16_bf16(A, ef[ks], a, 0,0,0);
    }

    // C. per-wave spin: both source flags polled in ONE loop (lane0)
    if (t > 0 && lane == 0){
      const int* fA = cnt + (g*8+sA)*32;
      const int* fB = cnt + (g*8+sB)*32;
      bool needA = (sA != s), needB = (sB != s);
      int guard = 0;
      while (needA || needB){
        if (needA && __hip_atomic_load(fA, __ATOMIC_RELAXED,
                                       __HIP_MEMORY_SCOPE_AGENT) >= t) needA = false;
        if (needB && __hip_atomic_load(fB, __ATOMIC_RELAXED,
                                       __HIP_MEMORY_SCOPE_AGENT) >= t) needB = false;
        if (needA || needB){
          if (++guard > (1<<20)) break;   // bail -> wrong result, not a hang
          __builtin_amdgcn_s_sleep(1);
        }
      }
    }

    // D. stage this wave's frags (skip own slice). 16B coherent loads.
    const size_t cbuf = ((size_t)(t&1)) << 21;
    short8 dv0, dv1, dv2, dv3;
    {
      const char* pb = (const char*)hgF + cbuf + (((size_t)(g*64 + w*4)) << 10) + lane*16;
      if (((w*4+0) & 15) >> 1 != s)
        asm volatile("global_load_dwordx4 %0, %1, off sc0 sc1" : "=&v"(dv0) : "v"(pb)        : "memory");
      if (((w*4+1) & 15) >> 1 != s)
        asm volatile("global_load_dwordx4 %0, %1, off sc0 sc1" : "=&v"(dv1) : "v"(pb+1024)   : "memory");
      if (((w*4+2) & 15) >> 1 != s)
        asm volatile("global_load_dwordx4 %0, %1, off sc0 sc1" : "=&v"(dv2) : "v"(pb+2048)   : "memory");
      if (((w*4+3) & 15) >> 1 != s)
        asm volatile("global_load_dwordx4 %0, %1, off sc0 sc1" : "=&v"(dv3) : "v"(pb+3072)   : "memory");
    }
    asm volatile("s_waitcnt vmcnt(0)" ::: "memory");
    __builtin_amdgcn_sched_barrier(0);
    {
      char* db = hbuf + ((w*4) << 10) + lane*16;
      if (((w*4+0) & 15) >> 1 != s) *(short8*)(db)        = dv0;
      if (((w*4+1) & 15) >> 1 != s) *(short8*)(db + 1024) = dv1;
      if (((w*4+2) & 15) >> 1 != s) *(short8*)(db + 2048) = dv2;
      if (((w*4+3) & 15) >> 1 != s) *(short8*)(db + 3072) = dv3;
    }
    __syncthreads();   // bar1: hbuf fully staged

    // E. h-part MFMA (B-frags contiguous from LDS, conflict-free)
    #pragma unroll
    for (int ks=0; ks<16; ++ks){
      short8 A  = *(const short8*)(abase + ((8+ks)<<10));
      short8 Bv = *(const short8*)(hfb + (ks<<10));
      a = __builtin_amdgcn_mfma_f32_32x32x16_bf16(A, Bv, a, 0,0,0);
    }
    __syncthreads();   // bar2: all hbuf reads done

    // F. pointwise -> h(t+1) overlay into own-slice frags
    #pragma unroll
    for (int r2=0; r2<4; ++r2){
      float gi = sigm_(a[r2*4+0] + biasr[r2*4+0]);
      float gf = sigm_(a[r2*4+1] + biasr[r2*4+1]);
      float gg = tanh_(a[r2*4+2] + biasr[r2*4+2]);
      float go = sigm_(a[r2*4+3] + biasr[r2*4+3]);
      float cn = gf*c[r2] + gi*gg;
      c[r2] = cn;
      float hn = go * tanh_(cn);
      int hl = nf*8 + 2*r2 + l5;          // col within slice [0,32)
      int fr = bg*16 + s*2 + (hl>>4);
      int cl = hl & 15;
      *(unsigned short*)(hbuf + (fr<<10) + (l31 + ((cl>>3)<<5))*16 + (cl&7)*2) = f2bf(hn);
    }
    __syncthreads();   // bar3: overlay complete

    // G. repack own-slice frags -> hgF[(t+1)&1], then post flag (R17 form)
    if (t < T_-1){
      if (w < 8){
        int bgr = w >> 1, kwl = w & 1;
        int fr = bgr*16 + s*2 + kwl;
        short8 hv8 = *(const short8*)(hbuf + (fr<<10) + lane*16);
        union { short8 sv; unsigned long long u[2]; } cv; cv.sv = hv8;
        unsigned long long* dstp = (unsigned long long*)((char*)hgF
            + (((size_t)((t+1)&1))<<21)
            + (((size_t)(g*64 + fr)) << 10) + lane*16);
        __hip_atomic_store(dstp,   cv.u[0], __ATOMIC_RELAXED, __HIP_MEMORY_SCOPE_AGENT);
        __hip_atomic_store(dstp+1, cv.u[1], __ATOMIC_RELAXED, __HIP_MEMORY_SCOPE_AGENT);
      }
      __syncthreads();  // bar4: stores drained (vmcnt0 before s_barrier)
      if (tid == 0)
        __hip_atomic_fetch_add(cnt + (g*8+s)*32, 1, __ATOMIC_RELAXED,
                               __HIP_MEMORY_SCOPE_AGENT);
    }

    // H. write-pass (after post; reads ONLY own-slice frags -> disjoint
    // from next step's D, which skips own-slice)
    u32x2 hb = *(const u32x2*)(hbuf + hfo);
    f32x4 hf;
    hf[0] = bf2f((unsigned short)(hb[0] & 0xFFFFu));
    hf[1] = bf2f((unsigned short)(hb[0] >> 16));
    hf[2] = bf2f((unsigned short)(hb[1] & 0xFFFFu));
    hf[3] = bf2f((unsigned short)(hb[1] >> 16));
    float* ltp = ltr + (size_t)t*H_;
    if (t < T_-1){
      f32x4 d;
      d[0] = fabsf(hf[0] - xv[0]);
      d[1] = fabsf(hf[1] - xv[1]);
      d[2] = fabsf(hf[2] - xv[2]);
      d[3] = fabsf(hf[3] - xv[3]);
      __builtin_nontemporal_store(d, (f32x4*)ltp);
      ldim += d;
      float ss = d[0]*d[0] + d[1]*d[1] + d[2]*d[2] + d[3]*d[3];
      ss += __shfl_xor(ss, 1);
      ss += __shfl_xor(ss, 2);
      ss += __shfl_xor(ss, 4);
      if ((lane & 7) == 0)
        psq[((size_t)t*8 + s)*4096 + b0 + row2] = f2bf(ss);
    } else {
      __builtin_nontemporal_store((f32x4)0.f, (f32x4*)ltp);
      __builtin_nontemporal_store(hf,
          (f32x4*)(out_hn + (size_t)(b0+row2)*H_ + s*32 + cloc));
    }
  }

  // epilogue: loss_dim
  *(f32x4*)(out_ldim + (size_t)(b0+row2)*H_ + s*32 + cloc) = ldim * (1.f/63.f);
}

// ---------------------------------------------------------------------------
// final: loss[b] = (1/63) sum_t sqrt(sum_s psq[t][s][b]).
// grid 64 x 256: 4 waves split t-range, LDS combine.
// ---------------------------------------------------------------------------
__global__ __launch_bounds__(256) void final_kernel(
    const unsigned short* __restrict__ psq, float* __restrict__ out_loss){
  __shared__ float part[4][64];
  const int w = threadIdx.x >> 6, lane = threadIdx.x & 63;
  const int b = blockIdx.x*64 + lane;
  const int t0 = w*16;
  const int nt = (w==3) ? 15 : 16;
  float lacc = 0.f;
  for (int ti=0; ti<nt; ++ti){
    int t = t0 + ti;
    float sum = 0.f;
    #pragma unroll
    for (int s=0;s<8;s++) sum += bf2f(psq[((size_t)t*8 + s)*4096 + b]);
    lacc += sqrtf(sum);
  }
  part[w][lane] = lacc;
  __syncthreads();
  if (w == 0)
    out_loss[b] = (part[0][lane]+part[1][lane]+part[2][lane]+part[3][lane])
                  * (1.f/63.f);
}

// ---------------------------------------------------------------------------
extern "C" void kernel_launch(void* const* d_in, const int* in_sizes, int n_in,
                              void* d_out, int out_size, void* d_ws, size_t ws_size,
                              hipStream_t stream){
  const float* x     = (const float*)d_in[0];
  const float* W_enc = (const float*)d_in[1];
  const float* b_enc = (const float*)d_in[2];
  const float* W_ih  = (const float*)d_in[3];
  const float* b_ih  = (const float*)d_in[4];
  const float* W_hh  = (const float*)d_in[5];
  const float* b_hh  = (const float*)d_in[6];

  // ws: encF 64MB | Wf 768KB | biasc 4KB | hgF 4MB | cnt 32KB | psq 4MB
  char* ws = (char*)d_ws;
  unsigned short* encF  = (unsigned short*)(ws);                 // 67,108,864
  unsigned short* Wf    = (unsigned short*)(ws + 67108864);      //    786,432
  float*          biasc = (float*)         (ws + 67895296);      //      4,096
  unsigned short* hgF   = (unsigned short*)(ws + 67899392);      //  4,194,304
  int*            cnt   = (int*)           (ws + 72093696);      //     32,768
  unsigned short* psq   = (unsigned short*)(ws + 72126464);      //  4,128,768

  float* out_hn   = (float*)d_out;
  float* out_loss = out_hn  + (size_t)B_*H_;
  float* out_ldim = out_loss + B_;
  float* out_ldt  = out_ldim + (size_t)B_*H_;

  (void)hipFuncSetAttribute((const void*)rec_kernel,
      hipFuncAttributeMaxDynamicSharedMemorySize, 163840);

  init_kernel<<<1536, 256, 0, stream>>>(W_ih, b_ih, W_hh, b_hh, Wf, biasc, hgF, cnt);
  enc_kernel<<<2048, 256, 0, stream>>>(x, W_enc, b_enc, encF);
  rec_kernel<<<256, 1024, 163840, stream>>>(encF, Wf, biasc, x, hgF, cnt, psq,
                                            out_hn, out_ldim, out_ldt);
  final_kernel<<<64, 256, 0, stream>>>(psq, out_loss);
}